// Round 1
// baseline (226.047 us; speedup 1.0000x reference)
//
#include <hip/hip_runtime.h>

namespace {
constexpr int kB = 4, kC = 32, kH = 512, kW = 512, kN = 64;
constexpr int kHout = 16, kMaxW = 192;
constexpr long long kResultElems = (long long)kB * kN * kC * kHout * kMaxW;
constexpr int kWaves = 3;                    // 192 threads
}

// One block per (b, n, i); 3 waves. BARRIER-FREE: each wave owns channels
// {w, w+3, ...}, stages the two bilinear source rows (y0,y1) for its channel
// into its PRIVATE LDS region with coalesced float4 loads, then samples all
// 192 output columns itself (3 chunks of 64 lanes). No __syncthreads.
//
// R5 changes vs the 222.6us baseline:
//  1. XCD swizzle: blockIdx round-robins XCDs (blk%8). Remap so each XCD owns
//     32 contiguous bn, with the 16 i-blocks of a bn adjacent in dispatch
//     order on that XCD -> shared source rows become L2 hits instead of
//     8 separate LLC fetches.
//  2. Nontemporal result/mask stores: output (101 MB) is never re-read;
//     'nt' keeps image rows resident in L2/LLC (235 MB footprint vs 256 MB).
//  3. One-channel register prefetch (issue-early/write-late): channel c+3's
//     four float4 loads are issued BEFORE the lgkmcnt fence; the fence's
//     memory clobber pins them above the compute phase so their ~LLC-hit
//     latency hides under sampling instead of serializing each iteration.
extern "C" __global__ __launch_bounds__(kWaves * 64) void roi_rotate(
    const float* __restrict__ image,
    const float* __restrict__ boxes,
    float* __restrict__ result,
    float* __restrict__ mask)
{
    __shared__ float ls[kWaves][2][kW];      // 12 KiB, wave-private regions

    // XCD-aware decode: grid = 4096 = 8 xcd * 32 bn * 16 i.
    const int blk  = blockIdx.x;
    const int xcd  = blk & 7;                // empirical round-robin xcd id
    const int slot = blk >> 3;               // dispatch order within xcd
    const int bn   = (xcd << 5) | (slot >> 4);   // 32 bn per xcd, i adjacent
    const int i    = slot & 15;              // output row 0..15
    const int b    = bn >> 6;

    const int tid  = threadIdx.x;
    const int w    = tid >> 6;               // wave id 0..2
    const int lane = tid & 63;

    const float* bx = boxes + bn * 5;
    const float left = bx[0];
    const float top  = bx[1];
    const float bw   = __fsub_rn(bx[2], bx[0]);
    const float bh   = __fsub_rn(bx[3], bx[1]);
    const int width  = (int)(__fmul_rn(__fdiv_rn(bw, bh), (float)kHout));
    const float each_w = __fdiv_rn(bw, (float)(width - 1));
    const float each_h = __fdiv_rn(bh, (float)(kHout - 1));

    // y taps: uniform over the block (depend only on i).
    const float y = __fadd_rn(__fmul_rn((float)i, each_h), top);
    const int yf = (int)floorf(y);
    const int y0 = min(max(yf,     0), kH - 1);
    const int y1 = min(max(yf + 1, 0), kH - 1);
    const float wy1 = (float)y1 - y;
    const float wy0 = y - (float)y0;

    // Staging extent (block-uniform). For valid j: x in [left, left+bw], so
    // x0 >= xlo and x1 <= xhi. float4 tails over-read <= 3 floats and stay
    // inside the image allocation.
    const int xlo = (min(max((int)floorf(left), 0), kW - 1)) & ~3;  // 16B align
    const int xhi = min((int)floorf(__fadd_rn(left, bw)) + 1, kW - 1);
    const int S   = xhi - xlo + 1;           // <= 512

    // Per-lane x taps for its 3 output columns j = 64q + lane.
    int   lx0q[3], lx1q[3];
    float waq[3], wbq[3], wcq[3], wdq[3];
    bool  vq[3];
    #pragma unroll
    for (int q = 0; q < 3; ++q) {
        const int j = 64 * q + lane;
        const float x = __fadd_rn(__fmul_rn((float)j, each_w), left);
        const int xf = (int)floorf(x);
        const int x0 = min(max(xf,     0), kW - 1);
        const int x1 = min(max(xf + 1, 0), kW - 1);
        const float wx1 = (float)x1 - x;
        const float wx0 = x - (float)x0;
        lx0q[q] = x0 - xlo;
        lx1q[q] = x1 - xlo;
        waq[q] = wx1 * wy1;
        wbq[q] = wx1 * wy0;
        wcq[q] = wx0 * wy1;
        wdq[q] = wx0 * wy0;
        vq[q]  = (j < width);
    }

    // Mask write early (independent of staging) so it overlaps the first loads.
    if (i == 0 && w == 0) {
        #pragma unroll
        for (int q = 0; q < 3; ++q) {
            __builtin_nontemporal_store(vq[q] ? 1.0f : 0.0f,
                                        mask + bn * kMaxW + 64 * q + lane);
        }
    }

    // Staging: lane covers 16B chunks at float offsets 4*lane and 4*(lane+64).
    const bool need0 = (4 * lane        < S);
    const bool need1 = (4 * (lane + 64) < S);
    const int  o0 = 4 * lane;
    const int  o1 = 4 * (lane + 64);
    const size_t r0 = (size_t)y0 * kW + xlo;
    const size_t r1 = (size_t)y1 * kW + xlo;

    const float* chbase = image + (size_t)b * ((size_t)kC * kH * kW);
    constexpr size_t kChStride = (size_t)kH * kW;
    float* opb = result + (size_t)bn * (kC * kHout * kMaxW) + (size_t)i * kMaxW;

    // Prologue: load this wave's first channel into registers.
    float4 a0, b0, a1, b1;
    {
        const float* p = chbase + (size_t)w * kChStride;
        if (need0) { a0 = *(const float4*)(p + r0 + o0);
                     b0 = *(const float4*)(p + r1 + o0); }
        if (need1) { a1 = *(const float4*)(p + r0 + o1);
                     b1 = *(const float4*)(p + r1 + o1); }
    }

    for (int c = w; c < kC; c += kWaves) {
        // Write the registers staged last iteration (compiler inserts the
        // vmcnt wait; those loads have had a full compute phase to land).
        if (need0) { *(float4*)&ls[w][0][o0] = a0;
                     *(float4*)&ls[w][1][o0] = b0; }
        if (need1) { *(float4*)&ls[w][0][o1] = a1;
                     *(float4*)&ls[w][1][o1] = b1; }

        // Issue NEXT channel's loads now; the lgkmcnt fence below has a
        // memory clobber, so these cannot sink past it into/below compute.
        const int cn = c + kWaves;
        if (cn < kC) {
            const float* pn = chbase + (size_t)cn * kChStride;
            if (need0) { a0 = *(const float4*)(pn + r0 + o0);
                         b0 = *(const float4*)(pn + r1 + o0); }
            if (need1) { a1 = *(const float4*)(pn + r0 + o1);
                         b1 = *(const float4*)(pn + r1 + o1); }
        }

        // Wave-synchronous fence: ds_writes complete before ds_reads below;
        // clobber stops the compiler migrating LDS ops across.
        __asm__ volatile("s_waitcnt lgkmcnt(0)" ::: "memory");

        float* op = opb + (size_t)c * (kHout * kMaxW);
        #pragma unroll
        for (int q = 0; q < 3; ++q) {
            float out = 0.0f;
            if (vq[q]) {
                out = ls[w][0][lx0q[q]] * waq[q] + ls[w][1][lx0q[q]] * wbq[q]
                    + ls[w][0][lx1q[q]] * wcq[q] + ls[w][1][lx1q[q]] * wdq[q];
            }
            // Streaming store: never re-read; don't evict image from L2/LLC.
            __builtin_nontemporal_store(out, op + 64 * q + lane);
        }
        // WAR guard: next iteration's ds_writes must not hoist above reads.
        __asm__ volatile("" ::: "memory");
    }
}

extern "C" void kernel_launch(void* const* d_in, const int* in_sizes, int n_in,
                              void* d_out, int out_size, void* d_ws, size_t ws_size,
                              hipStream_t stream) {
    const float* image = (const float*)d_in[0];
    const float* boxes = (const float*)d_in[1];
    float* result = (float*)d_out;
    float* mask   = result + kResultElems;   // outputs concatenated flat

    dim3 grid(kB * kN * kHout);   // 4096 blocks: 8 xcd x 32 bn x 16 i
    dim3 block(kWaves * 64);      // 192 threads = 3 independent waves
    hipLaunchKernelGGL(roi_rotate, grid, block, 0, stream,
                       image, boxes, result, mask);
}